// Round 8
// baseline (206.211 us; speedup 1.0000x reference)
//
#include <hip/hip_runtime.h>

// ---------------------------------------------------------------------------
// FlashAttention block: out = proj(causal_attn(qkv(x)))
// B=2, T=2048, D=1024, H=16, dhead=64.  All GEMMs + attention in bf16 MFMA
// (16x16x32), fp32 accumulate.  fp32 output.
// R8: attn software pipeline — PV of tile t-1 (register-only MFMAs: P-frags +
// V-frags held in regs) overlaps the S/softmax chain of tile t; wave-max
// deferred one tile (exact: PV lands before the rescale that retires it).
// Gemms/converts unchanged from R7 for clean attribution.
// ---------------------------------------------------------------------------

#define B_   2
#define T_   2048
#define D_   1024
#define H_   16
#define DH_  64
#define M_   (B_ * T_)       // 4096
#define N1_  (3 * D_)        // 3072
// qscale folds 1/sqrt(dhead) and log2(e) so softmax uses native exp2
#define QSCALE (0.125f * 1.44269504088896340736f)

typedef __bf16 bf16x8 __attribute__((ext_vector_type(8)));
typedef __bf16 bf16x4 __attribute__((ext_vector_type(4)));
typedef float  f32x4  __attribute__((ext_vector_type(4)));

#define MFMA16(a, b, c) __builtin_amdgcn_mfma_f32_16x16x32_bf16((a), (b), (c), 0, 0, 0)

// async global->LDS, 16B per lane; LDS dest = base + lane*16 (wave-uniform base)
#define GLOAD16(gp, lp)                                                        \
    __builtin_amdgcn_global_load_lds(                                          \
        (const __attribute__((address_space(1))) void*)(gp),                   \
        (__attribute__((address_space(3))) void*)(lp), 16, 0, 0)

#define DRAIN_ALL() __asm__ volatile("s_waitcnt vmcnt(0) lgkmcnt(0)" ::: "memory")

// -------------------------------- converts ---------------------------------

__global__ void f32_to_bf16_kernel(const float* __restrict__ in,
                                   __bf16* __restrict__ out, int n) {
    int i = (blockIdx.x * blockDim.x + threadIdx.x) * 4;
    if (i + 3 < n) {
        float4 f = *(const float4*)(in + i);
        bf16x4 o;
        o[0] = (__bf16)f.x; o[1] = (__bf16)f.y; o[2] = (__bf16)f.z; o[3] = (__bf16)f.w;
        *(bf16x4*)(out + i) = o;
    }
}

// in: fp32 [R][C]  ->  out: bf16 [C][R]
__global__ void transpose_bf16_kernel(const float* __restrict__ in,
                                      __bf16* __restrict__ out, int R, int C) {
    __shared__ float tile[32][33];
    int tx = threadIdx.x;          // 0..31
    int ty = threadIdx.y;          // 0..7
    int c0 = blockIdx.x * 32;
    int r0 = blockIdx.y * 32;
#pragma unroll
    for (int i = 0; i < 4; i++)
        tile[ty + i * 8][tx] = in[(size_t)(r0 + ty + i * 8) * C + c0 + tx];
    __syncthreads();
#pragma unroll
    for (int i = 0; i < 4; i++)
        out[(size_t)(c0 + ty + i * 8) * R + r0 + tx] = (__bf16)tile[tx][ty + i * 8];
}

// ------------------------------- MFMA GEMM ---------------------------------
// C[M][N] = A[M][K] @ Bt[N][K]^T + bias.  TM x 128 tile, 256 threads (4
// waves), wave covers (TM/2) x 64 as (TM/32)x4 frags of 16x16, BK=32.
// Double-buffered global_load_lds staging with next-tile prefetch.
// EPI 0: scatter to Q (scaled), K, Vt (bf16).  EPI 1: fp32 out + bias.

template <int EPI, int TM>
__global__ __launch_bounds__(256) void gemm_bt_kernel(
    const __bf16* __restrict__ A, const __bf16* __restrict__ Bt,
    const float* __restrict__ bias, float* __restrict__ Cout,
    __bf16* __restrict__ Q, __bf16* __restrict__ Kb, __bf16* __restrict__ Vt,
    int M, int N, int K) {
    constexpr int MI  = TM / 32;          // m-frags per wave (4 or 2)
    constexpr int WM  = MI * 16;          // rows per wave (64 or 32)
    constexpr int ACH = TM / 64;          // A-chunk rounds (2 or 1)
    __shared__ __bf16 As[2][TM * 32];     // row-major [TM][32]
    __shared__ __bf16 Bs[2][128 * 32];

    const int tid  = threadIdx.x;
    const int lane = tid & 63;
    const int wave = tid >> 6;
    const int lo   = lane & 15;
    const int qd   = lane >> 4;
    const int wm   = (wave >> 1) * WM;
    const int wn   = (wave & 1) * 64;
    const int m0   = blockIdx.y * TM;
    const int n0   = blockIdx.x * 128;

    // chunk g (16B) -> LDS byte g*16; global row g>>2, k-off (g&3)*8
    const __bf16* gA[ACH];
    const __bf16* gB[2];
#pragma unroll
    for (int c = 0; c < ACH; c++) {
        int g = tid + 256 * c;
        gA[c] = A + (size_t)(m0 + (g >> 2)) * K + (g & 3) * 8;
    }
#pragma unroll
    for (int c = 0; c < 2; c++) {
        int g = tid + 256 * c;
        gB[c] = Bt + (size_t)(n0 + (g >> 2)) * K + (g & 3) * 8;
    }

    f32x4 acc[MI][4] = {};
    const int nk = K >> 5;

    // prologue: stage tile 0 into buffer 0
#pragma unroll
    for (int c = 0; c < ACH; c++)
        GLOAD16(gA[c], (__bf16*)As[0] + (tid + 256 * c) * 8);
#pragma unroll
    for (int c = 0; c < 2; c++)
        GLOAD16(gB[c], (__bf16*)Bs[0] + (tid + 256 * c) * 8);
    DRAIN_ALL();
    __syncthreads();

    for (int kt = 0; kt < nk; kt++) {
        const int cur = kt & 1;
        if (kt + 1 < nk) {               // prefetch next tile into other buffer
            const int k0n = (kt + 1) << 5;
#pragma unroll
            for (int c = 0; c < ACH; c++)
                GLOAD16(gA[c] + k0n, (__bf16*)As[1 - cur] + (tid + 256 * c) * 8);
#pragma unroll
            for (int c = 0; c < 2; c++)
                GLOAD16(gB[c] + k0n, (__bf16*)Bs[1 - cur] + (tid + 256 * c) * 8);
        }
        bf16x8 af[MI], bfr[4];
#pragma unroll
        for (int i = 0; i < MI; i++)
            af[i] = *(const bf16x8*)(As[cur] + (wm + i * 16 + lo) * 32 + qd * 8);
#pragma unroll
        for (int j = 0; j < 4; j++)
            bfr[j] = *(const bf16x8*)(Bs[cur] + (wn + j * 16 + lo) * 32 + qd * 8);
#pragma unroll
        for (int i = 0; i < MI; i++)
#pragma unroll
            for (int j = 0; j < 4; j++)
                acc[i][j] = MFMA16(af[i], bfr[j], acc[i][j]);
        DRAIN_ALL();                     // prefetch landed + all LDS ops done
        __syncthreads();
    }

#pragma unroll
    for (int i = 0; i < MI; i++) {
#pragma unroll
        for (int j = 0; j < 4; j++) {
#pragma unroll
            for (int r = 0; r < 4; r++) {
                int gm = m0 + wm + i * 16 + qd * 4 + r;   // C/D row
                int gn = n0 + wn + j * 16 + lo;           // C/D col
                float v = acc[i][j][r] + bias[gn];
                if (EPI == 1) {
                    Cout[(size_t)gm * N + gn] = v;
                } else {
                    int which = gn >> 10;                 // 0=q 1=k 2=v
                    int bh = ((gm >> 11) << 4) + ((gn >> 6) & 15);
                    int dd = gn & 63;
                    int t  = gm & (T_ - 1);
                    if (which == 0)
                        Q[((size_t)bh * T_ + t) * DH_ + dd] = (__bf16)(v * QSCALE);
                    else if (which == 1)
                        Kb[((size_t)bh * T_ + t) * DH_ + dd] = (__bf16)v;
                    else
                        Vt[((size_t)bh * DH_ + dd) * T_ + t] = (__bf16)v;
                }
            }
        }
    }
}

// ---------------------------- flash attention ------------------------------
// Persistent snake schedule (as R7): 1024 items, heavy-first, head pinned to
// XCD; block k takes item k, blocks >=512 also take 1535-k; grid 768.
// R8 pipeline per K-tile: PV of tile t-1 runs as register-only MFMAs (P-frags
// pa*, V-frags vb[] read into regs in iter t-1) at the top of iter t,
// overlapping tile t's S/softmax chain.  Wave-max deferred one tile: m
// updates from lm_{t-1} AFTER PV_{t-1} lands (exact rescale ordering);
// overflow bound 2^(tile-to-tile max growth) << bf16 range.

__global__ __launch_bounds__(256) void attn_kernel(
    const __bf16* __restrict__ Q,   // [BH][T][64], pre-scaled
    const __bf16* __restrict__ Kb,  // [BH][T][64]
    const __bf16* __restrict__ Vt,  // [BH][64][T]
    __bf16* __restrict__ O) {       // [B][T][H*64]
    __shared__ __bf16 Ks[2][64 * 64];     // [key][d]  2 x 8 KB, swizzled
    __shared__ __bf16 Vs[2][64 * 64];     // [d][key]  2 x 8 KB, swizzled
    __shared__ __bf16 Ps[4][16][72];      // per-wave P transpose buffer

    const int tid  = threadIdx.x;
    const int wave = tid >> 6;
    const int lane = tid & 63;
    const int lo   = lane & 15;
    const int qd   = lane >> 4;

    // staging decode: chunk g -> LDS byte g*16; row=g>>3, cc_lds=g&7,
    // global cc = cc_lds ^ (row&7)
    const int g0  = wave * 128 + lane;
    const int g1  = g0 + 64;
    const int r0s = g0 >> 3, c0s = (g0 & 7) ^ (r0s & 7);
    const int r1s = g1 >> 3, c1s = (g1 & 7) ^ (r1s & 7);
    const int so0 = wave * 1024;
    const int so1 = wave * 1024 + 512;

    bf16x8 ones;
#pragma unroll
    for (int i = 0; i < 8; i++) ones[i] = (__bf16)1.0f;

    const int kblk   = blockIdx.x;
    const int nitems = (kblk >= 512) ? 2 : 1;

    for (int it = 0; it < nitems; it++) {
        const int item = (it == 0) ? kblk : (1535 - kblk);
        const int x    = 31 - (item >> 5);
        const int bh   = item & 31;
        const int b    = bh >> 4;
        const int h    = bh & 15;
        const int q0   = x * 64 + wave * 16;

        const __bf16* Qh = Q + (size_t)bh * T_ * DH_;
        const __bf16* Kh = Kb + (size_t)bh * T_ * DH_;
        const __bf16* Vh = Vt + (size_t)bh * DH_ * T_;

        // Q A-frags: lane holds Q[q0+lo][half*32 + qd*8 + j]
        bf16x8 qa0 = *(const bf16x8*)(Qh + (size_t)(q0 + lo) * DH_ + qd * 8);
        bf16x8 qa1 = *(const bf16x8*)(Qh + (size_t)(q0 + lo) * DH_ + 32 + qd * 8);

        f32x4 oacc[4] = {};
        float lrow[4] = {0.0f, 0.0f, 0.0f, 0.0f};
        float m, lmprev;                  // running max; tile max pending
        bf16x8 pa0, pa1;                  // P frags of previous tile
        bf16x8 vb[8];                     // V frags of previous tile
        const int qrow  = q0 + qd * 4;
        const int ntile = x + 1;

        // prologue: stage tile 0 into buffer 0 (prev item fully synced)
        GLOAD16(Kh + (size_t)r0s * DH_ + c0s * 8, Ks[0] + so0);
        GLOAD16(Kh + (size_t)r1s * DH_ + c1s * 8, Ks[0] + so1);
        GLOAD16(Vh + (size_t)r0s * T_ + c0s * 8, Vs[0] + so0);
        GLOAD16(Vh + (size_t)r1s * T_ + c1s * 8, Vs[0] + so1);
        DRAIN_ALL();
        __syncthreads();

        // ================= peeled tile 0 (synchronous max) =================
        {
            if (ntile > 1) {             // prefetch tile 1
                GLOAD16(Kh + (size_t)(64 + r0s) * DH_ + c0s * 8, Ks[1] + so0);
                GLOAD16(Kh + (size_t)(64 + r1s) * DH_ + c1s * 8, Ks[1] + so1);
                GLOAD16(Vh + (size_t)r0s * T_ + 64 + c0s * 8, Vs[1] + so0);
                GLOAD16(Vh + (size_t)r1s * T_ + 64 + c1s * 8, Vs[1] + so1);
            }
            f32x4 s[4] = {};
#pragma unroll
            for (int g = 0; g < 4; g++) {
                const int row = g * 16 + lo;
                const __bf16* kr = Ks[0] + row * 64;
                bf16x8 kb0 = *(const bf16x8*)(kr + ((qd ^ (row & 7)) << 3));
                bf16x8 kb1 = *(const bf16x8*)(kr + (((4 + qd) ^ (row & 7)) << 3));
                s[g] = MFMA16(qa0, kb0, s[g]);
                s[g] = MFMA16(qa1, kb1, s[g]);
            }
            if (63 > q0) {               // diagonal tile mask (x==0 items)
#pragma unroll
                for (int g = 0; g < 4; g++) {
                    const int col = g * 16 + lo;
#pragma unroll
                    for (int r = 0; r < 4; r++)
                        s[g][r] = (col <= qrow + r) ? s[g][r] : -1e30f;
                }
            }
            float lm = s[0][0];
#pragma unroll
            for (int g = 0; g < 4; g++)
#pragma unroll
                for (int r = 0; r < 4; r++) lm = fmaxf(lm, s[g][r]);
#pragma unroll
            for (int off = 1; off < 64; off <<= 1)
                lm = fmaxf(lm, __shfl_xor(lm, off));
            m = lm;
            lmprev = lm;
#pragma unroll
            for (int g = 0; g < 4; g++)
#pragma unroll
                for (int r = 0; r < 4; r++)
                    Ps[wave][qd * 4 + r][g * 16 + lo] =
                        (__bf16)__builtin_amdgcn_exp2f(s[g][r] - m);
            __asm__ volatile("s_waitcnt lgkmcnt(0)" ::: "memory");
            pa0 = *(const bf16x8*)(&Ps[wave][lo][qd * 8]);
            pa1 = *(const bf16x8*)(&Ps[wave][lo][32 + qd * 8]);
#pragma unroll
            for (int c = 0; c < 4; c++) {
                const int row = c * 16 + lo;
                const __bf16* vr = Vs[0] + row * 64;
                vb[c * 2]     = *(const bf16x8*)(vr + ((qd ^ (row & 7)) << 3));
                vb[c * 2 + 1] = *(const bf16x8*)(vr + (((4 + qd) ^ (row & 7)) << 3));
            }
            DRAIN_ALL();
            __syncthreads();
        }

        // ======================= pipelined tiles 1.. =======================
        for (int t = 1; t < ntile; t++) {
            const int j0  = t << 6;
            const int cur = t & 1;
            if (t + 1 < ntile) {         // prefetch next K/V tile
                const int j0n = j0 + 64;
                GLOAD16(Kh + (size_t)(j0n + r0s) * DH_ + c0s * 8, Ks[1 - cur] + so0);
                GLOAD16(Kh + (size_t)(j0n + r1s) * DH_ + c1s * 8, Ks[1 - cur] + so1);
                GLOAD16(Vh + (size_t)r0s * T_ + j0n + c0s * 8, Vs[1 - cur] + so0);
                GLOAD16(Vh + (size_t)r1s * T_ + j0n + c1s * 8, Vs[1 - cur] + so1);
            }

            // ---- PV of tile t-1: register-only MFMAs (pipe filler) ----
            f32x4 ps = {};
            ps = MFMA16(pa0, ones, ps);
            ps = MFMA16(pa1, ones, ps);
#pragma unroll
            for (int c = 0; c < 4; c++) {
                oacc[c] = MFMA16(pa0, vb[c * 2], oacc[c]);
                oacc[c] = MFMA16(pa1, vb[c * 2 + 1], oacc[c]);
            }
#pragma unroll
            for (int r = 0; r < 4; r++) lrow[r] += ps[r];

            // ---- S_t = Q @ K_t ----
            f32x4 s[4] = {};
#pragma unroll
            for (int g = 0; g < 4; g++) {
                const int row = g * 16 + lo;
                const __bf16* kr = Ks[cur] + row * 64;
                bf16x8 kb0 = *(const bf16x8*)(kr + ((qd ^ (row & 7)) << 3));
                bf16x8 kb1 = *(const bf16x8*)(kr + (((4 + qd) ^ (row & 7)) << 3));
                s[g] = MFMA16(qa0, kb0, s[g]);
                s[g] = MFMA16(qa1, kb1, s[g]);
            }
            if (j0 + 63 > q0) {          // diagonal tile mask
#pragma unroll
                for (int g = 0; g < 4; g++) {
                    const int col = j0 + g * 16 + lo;
#pragma unroll
                    for (int r = 0; r < 4; r++)
                        s[g][r] = (col <= qrow + r) ? s[g][r] : -1e30f;
                }
            }

            // ---- deferred m update (uses lm of tile t-1; PV_{t-1} landed) --
            {
                const float mnew = fmaxf(m, lmprev);
                if (mnew > m) {          // wave-uniform
                    const float alpha = __builtin_amdgcn_exp2f(m - mnew);
#pragma unroll
                    for (int r = 0; r < 4; r++) lrow[r] *= alpha;
#pragma unroll
                    for (int c = 0; c < 4; c++)
#pragma unroll
                        for (int r = 0; r < 4; r++) oacc[c][r] *= alpha;
                    m = mnew;
                }
            }

            // ---- launch lm_t reduce (consumed next iter; off critical path)
            float lm = s[0][0];
#pragma unroll
            for (int g = 0; g < 4; g++)
#pragma unroll
                for (int r = 0; r < 4; r++) lm = fmaxf(lm, s[g][r]);
#pragma unroll
            for (int off = 1; off < 64; off <<= 1)
                lm = fmaxf(lm, __shfl_xor(lm, off));
            lmprev = lm;

            // ---- P_t = exp2(S_t - m): C-layout -> LDS -> A-layout ----
#pragma unroll
            for (int g = 0; g < 4; g++)
#pragma unroll
                for (int r = 0; r < 4; r++)
                    Ps[wave][qd * 4 + r][g * 16 + lo] =
                        (__bf16)__builtin_amdgcn_exp2f(s[g][r] - m);
            __asm__ volatile("s_waitcnt lgkmcnt(0)" ::: "memory");
            pa0 = *(const bf16x8*)(&Ps[wave][lo][qd * 8]);
            pa1 = *(const bf16x8*)(&Ps[wave][lo][32 + qd * 8]);

            // ---- V_t frags into registers (for next iter / epilogue) ----
#pragma unroll
            for (int c = 0; c < 4; c++) {
                const int row = c * 16 + lo;
                const __bf16* vr = Vs[cur] + row * 64;
                vb[c * 2]     = *(const bf16x8*)(vr + ((qd ^ (row & 7)) << 3));
                vb[c * 2 + 1] = *(const bf16x8*)(vr + (((4 + qd) ^ (row & 7)) << 3));
            }

            DRAIN_ALL();                 // prefetch landed + all LDS ops done
            __syncthreads();
        }

        // ---- epilogue: PV of final tile, normalize, store ----
        {
            f32x4 ps = {};
            ps = MFMA16(pa0, ones, ps);
            ps = MFMA16(pa1, ones, ps);
#pragma unroll
            for (int c = 0; c < 4; c++) {
                oacc[c] = MFMA16(pa0, vb[c * 2], oacc[c]);
                oacc[c] = MFMA16(pa1, vb[c * 2 + 1], oacc[c]);
            }
#pragma unroll
            for (int r = 0; r < 4; r++) lrow[r] += ps[r];
        }
        float inv[4];
#pragma unroll
        for (int r = 0; r < 4; r++) inv[r] = 1.0f / lrow[r];
#pragma unroll
        for (int c = 0; c < 4; c++) {
#pragma unroll
            for (int r = 0; r < 4; r++) {
                float val = oacc[c][r] * inv[r];
                size_t idx = ((size_t)b * T_ + (qrow + r)) * D_ + h * DH_ + c * 16 + lo;
                O[idx] = (__bf16)val;
            }
        }
    }
}

// -------------------------------- launcher ---------------------------------

extern "C" void kernel_launch(void* const* d_in, const int* in_sizes, int n_in,
                              void* d_out, int out_size, void* d_ws, size_t ws_size,
                              hipStream_t stream) {
    const float* x      = (const float*)d_in[0];
    const float* w_attn = (const float*)d_in[1];
    const float* b_attn = (const float*)d_in[2];
    const float* w_proj = (const float*)d_in[3];
    const float* b_proj = (const float*)d_in[4];
    float* out = (float*)d_out;

    const size_t MB = (size_t)1 << 20;
    if (ws_size < 48 * MB) return;   // need 48 MB scratch

    char* ws = (char*)d_ws;
    __bf16* xb     = (__bf16*)(ws);              //  8 MB  [M][D]
    __bf16* wattnT = (__bf16*)(ws + 8 * MB);     //  6 MB  [3D][D]
    __bf16* wprojT = (__bf16*)(ws + 14 * MB);    //  2 MB  [D][D]
    __bf16* Qb     = (__bf16*)(ws + 16 * MB);    //  8 MB  [BH][T][64]
    __bf16* Kb     = (__bf16*)(ws + 24 * MB);    //  8 MB  [BH][T][64]
    __bf16* Vt     = (__bf16*)(ws + 32 * MB);    //  8 MB  [BH][64][T]
    __bf16* Ob     = (__bf16*)(ws + 40 * MB);    //  8 MB  [M][D]

    // 1. converts
    f32_to_bf16_kernel<<<(M_ * D_) / 1024, 256, 0, stream>>>(x, xb, M_ * D_);
    transpose_bf16_kernel<<<dim3(N1_ / 32, D_ / 32), dim3(32, 8), 0, stream>>>(
        w_attn, wattnT, D_, N1_);
    transpose_bf16_kernel<<<dim3(D_ / 32, D_ / 32), dim3(32, 8), 0, stream>>>(
        w_proj, wprojT, D_, D_);
    // 2. QKV GEMM -> Q(scaled)/K/Vt
    gemm_bt_kernel<0, 128><<<dim3(N1_ / 128, M_ / 128), 256, 0, stream>>>(
        xb, wattnT, b_attn, nullptr, Qb, Kb, Vt, M_, N1_, D_);
    // 3. causal flash attention (persistent snake schedule, pipelined PV)
    attn_kernel<<<dim3(768), 256, 0, stream>>>(Qb, Kb, Vt, Ob);
    // 4. output projection (fp32 + bias), 64-row tiles for 2 blocks/CU
    gemm_bt_kernel<1, 64><<<dim3(D_ / 128, M_ / 64), 256, 0, stream>>>(
        Ob, wprojT, b_proj, out, nullptr, nullptr, nullptr, M_, D_, D_);
}

// Round 9
// 193.535 us; speedup vs baseline: 1.0655x; 1.0655x over previous
//
#include <hip/hip_runtime.h>

// ---------------------------------------------------------------------------
// FlashAttention block: out = proj(causal_attn(qkv(x)))
// B=2, T=2048, D=1024, H=16, dhead=64.  All GEMMs + attention in bf16 MFMA
// (16x16x32), fp32 accumulate.  fp32 output.
// R9: attn reverted to R7 (R8's register-pipelined PV regressed 55->72 us:
// +32 VGPR and the PV chain still sat before the same drain barrier).
// Both weight transposes merged into one launch.
// ---------------------------------------------------------------------------

#define B_   2
#define T_   2048
#define D_   1024
#define H_   16
#define DH_  64
#define M_   (B_ * T_)       // 4096
#define N1_  (3 * D_)        // 3072
// qscale folds 1/sqrt(dhead) and log2(e) so softmax uses native exp2
#define QSCALE (0.125f * 1.44269504088896340736f)

typedef __bf16 bf16x8 __attribute__((ext_vector_type(8)));
typedef __bf16 bf16x4 __attribute__((ext_vector_type(4)));
typedef float  f32x4  __attribute__((ext_vector_type(4)));

#define MFMA16(a, b, c) __builtin_amdgcn_mfma_f32_16x16x32_bf16((a), (b), (c), 0, 0, 0)

// async global->LDS, 16B per lane; LDS dest = base + lane*16 (wave-uniform base)
#define GLOAD16(gp, lp)                                                        \
    __builtin_amdgcn_global_load_lds(                                          \
        (const __attribute__((address_space(1))) void*)(gp),                   \
        (__attribute__((address_space(3))) void*)(lp), 16, 0, 0)

#define DRAIN_ALL() __asm__ volatile("s_waitcnt vmcnt(0) lgkmcnt(0)" ::: "memory")

// -------------------------------- converts ---------------------------------

__global__ void f32_to_bf16_kernel(const float* __restrict__ in,
                                   __bf16* __restrict__ out, int n) {
    int i = (blockIdx.x * blockDim.x + threadIdx.x) * 4;
    if (i + 3 < n) {
        float4 f = *(const float4*)(in + i);
        bf16x4 o;
        o[0] = (__bf16)f.x; o[1] = (__bf16)f.y; o[2] = (__bf16)f.z; o[3] = (__bf16)f.w;
        *(bf16x4*)(out + i) = o;
    }
}

// Both weight transposes in one launch.  in: fp32 [1024][C] -> out: bf16
// [C][1024].  blockIdx.x < 96: w_attn (C=3072); else w_proj (C=1024).
__global__ void transpose2_bf16_kernel(const float* __restrict__ in0,
                                       __bf16* __restrict__ out0,
                                       const float* __restrict__ in1,
                                       __bf16* __restrict__ out1) {
    __shared__ float tile[32][33];
    const int R = D_;
    int bx = blockIdx.x;
    const float* in;
    __bf16* out;
    int C;
    if (bx < N1_ / 32) { in = in0; out = out0; C = N1_; }
    else               { in = in1; out = out1; C = D_; bx -= N1_ / 32; }
    int tx = threadIdx.x;          // 0..31
    int ty = threadIdx.y;          // 0..7
    int c0 = bx * 32;
    int r0 = blockIdx.y * 32;
#pragma unroll
    for (int i = 0; i < 4; i++)
        tile[ty + i * 8][tx] = in[(size_t)(r0 + ty + i * 8) * C + c0 + tx];
    __syncthreads();
#pragma unroll
    for (int i = 0; i < 4; i++)
        out[(size_t)(c0 + ty + i * 8) * R + r0 + tx] = (__bf16)tile[tx][ty + i * 8];
}

// ------------------------------- MFMA GEMM ---------------------------------
// C[M][N] = A[M][K] @ Bt[N][K]^T + bias.  TM x 128 tile, 256 threads (4
// waves), wave covers (TM/2) x 64 as (TM/32)x4 frags of 16x16, BK=32.
// Double-buffered global_load_lds staging with next-tile prefetch.
// EPI 0: scatter to Q (scaled), K, Vt (bf16).  EPI 1: fp32 out + bias.

template <int EPI, int TM>
__global__ __launch_bounds__(256) void gemm_bt_kernel(
    const __bf16* __restrict__ A, const __bf16* __restrict__ Bt,
    const float* __restrict__ bias, float* __restrict__ Cout,
    __bf16* __restrict__ Q, __bf16* __restrict__ Kb, __bf16* __restrict__ Vt,
    int M, int N, int K) {
    constexpr int MI  = TM / 32;          // m-frags per wave (4 or 2)
    constexpr int WM  = MI * 16;          // rows per wave (64 or 32)
    constexpr int ACH = TM / 64;          // A-chunk rounds (2 or 1)
    __shared__ __bf16 As[2][TM * 32];     // row-major [TM][32]
    __shared__ __bf16 Bs[2][128 * 32];

    const int tid  = threadIdx.x;
    const int lane = tid & 63;
    const int wave = tid >> 6;
    const int lo   = lane & 15;
    const int qd   = lane >> 4;
    const int wm   = (wave >> 1) * WM;
    const int wn   = (wave & 1) * 64;
    const int m0   = blockIdx.y * TM;
    const int n0   = blockIdx.x * 128;

    // chunk g (16B) -> LDS byte g*16; global row g>>2, k-off (g&3)*8
    const __bf16* gA[ACH];
    const __bf16* gB[2];
#pragma unroll
    for (int c = 0; c < ACH; c++) {
        int g = tid + 256 * c;
        gA[c] = A + (size_t)(m0 + (g >> 2)) * K + (g & 3) * 8;
    }
#pragma unroll
    for (int c = 0; c < 2; c++) {
        int g = tid + 256 * c;
        gB[c] = Bt + (size_t)(n0 + (g >> 2)) * K + (g & 3) * 8;
    }

    f32x4 acc[MI][4] = {};
    const int nk = K >> 5;

    // prologue: stage tile 0 into buffer 0
#pragma unroll
    for (int c = 0; c < ACH; c++)
        GLOAD16(gA[c], (__bf16*)As[0] + (tid + 256 * c) * 8);
#pragma unroll
    for (int c = 0; c < 2; c++)
        GLOAD16(gB[c], (__bf16*)Bs[0] + (tid + 256 * c) * 8);
    DRAIN_ALL();
    __syncthreads();

    for (int kt = 0; kt < nk; kt++) {
        const int cur = kt & 1;
        if (kt + 1 < nk) {               // prefetch next tile into other buffer
            const int k0n = (kt + 1) << 5;
#pragma unroll
            for (int c = 0; c < ACH; c++)
                GLOAD16(gA[c] + k0n, (__bf16*)As[1 - cur] + (tid + 256 * c) * 8);
#pragma unroll
            for (int c = 0; c < 2; c++)
                GLOAD16(gB[c] + k0n, (__bf16*)Bs[1 - cur] + (tid + 256 * c) * 8);
        }
        bf16x8 af[MI], bfr[4];
#pragma unroll
        for (int i = 0; i < MI; i++)
            af[i] = *(const bf16x8*)(As[cur] + (wm + i * 16 + lo) * 32 + qd * 8);
#pragma unroll
        for (int j = 0; j < 4; j++)
            bfr[j] = *(const bf16x8*)(Bs[cur] + (wn + j * 16 + lo) * 32 + qd * 8);
#pragma unroll
        for (int i = 0; i < MI; i++)
#pragma unroll
            for (int j = 0; j < 4; j++)
                acc[i][j] = MFMA16(af[i], bfr[j], acc[i][j]);
        DRAIN_ALL();                     // prefetch landed + all LDS ops done
        __syncthreads();
    }

#pragma unroll
    for (int i = 0; i < MI; i++) {
#pragma unroll
        for (int j = 0; j < 4; j++) {
#pragma unroll
            for (int r = 0; r < 4; r++) {
                int gm = m0 + wm + i * 16 + qd * 4 + r;   // C/D row
                int gn = n0 + wn + j * 16 + lo;           // C/D col
                float v = acc[i][j][r] + bias[gn];
                if (EPI == 1) {
                    Cout[(size_t)gm * N + gn] = v;
                } else {
                    int which = gn >> 10;                 // 0=q 1=k 2=v
                    int bh = ((gm >> 11) << 4) + ((gn >> 6) & 15);
                    int dd = gn & 63;
                    int t  = gm & (T_ - 1);
                    if (which == 0)
                        Q[((size_t)bh * T_ + t) * DH_ + dd] = (__bf16)(v * QSCALE);
                    else if (which == 1)
                        Kb[((size_t)bh * T_ + t) * DH_ + dd] = (__bf16)v;
                    else
                        Vt[((size_t)bh * DH_ + dd) * T_ + t] = (__bf16)v;
                }
            }
        }
    }
}

// ---------------------------- flash attention ------------------------------
// R7 kernel (measured 54.9 us / MfmaUtil 14% / occ 24.8%).  Persistent snake
// schedule: 1024 items (head x 64-row q-tile), heavy-first, head pinned to
// XCD; block k takes item k, blocks >=512 also take 1535-k; grid 768 =
// 3 blocks/CU.  Softmax: shared per-wave m, wave-uniform skip-rescale, row
// sums via MFMA ones-trick.  K/V 64-key LDS tiles, dbuf + prefetch,
// XOR-swizzled rows.

__global__ __launch_bounds__(256) void attn_kernel(
    const __bf16* __restrict__ Q,   // [BH][T][64], pre-scaled
    const __bf16* __restrict__ Kb,  // [BH][T][64]
    const __bf16* __restrict__ Vt,  // [BH][64][T]
    __bf16* __restrict__ O) {       // [B][T][H*64]
    __shared__ __bf16 Ks[2][64 * 64];     // [key][d]  2 x 8 KB, swizzled
    __shared__ __bf16 Vs[2][64 * 64];     // [d][key]  2 x 8 KB, swizzled
    __shared__ __bf16 Ps[4][16][72];      // per-wave P transpose buffer

    const int tid  = threadIdx.x;
    const int wave = tid >> 6;
    const int lane = tid & 63;
    const int lo   = lane & 15;
    const int qd   = lane >> 4;

    // staging decode: chunk g -> LDS byte g*16; row=g>>3, cc_lds=g&7,
    // global cc = cc_lds ^ (row&7)
    const int g0  = wave * 128 + lane;
    const int g1  = g0 + 64;
    const int r0s = g0 >> 3, c0s = (g0 & 7) ^ (r0s & 7);
    const int r1s = g1 >> 3, c1s = (g1 & 7) ^ (r1s & 7);
    const int so0 = wave * 1024;
    const int so1 = wave * 1024 + 512;

    bf16x8 ones;
#pragma unroll
    for (int i = 0; i < 8; i++) ones[i] = (__bf16)1.0f;

    const int kblk   = blockIdx.x;
    const int nitems = (kblk >= 512) ? 2 : 1;

    for (int it = 0; it < nitems; it++) {
        const int item = (it == 0) ? kblk : (1535 - kblk);
        const int x    = 31 - (item >> 5);
        const int bh   = item & 31;
        const int b    = bh >> 4;
        const int h    = bh & 15;
        const int q0   = x * 64 + wave * 16;

        const __bf16* Qh = Q + (size_t)bh * T_ * DH_;
        const __bf16* Kh = Kb + (size_t)bh * T_ * DH_;
        const __bf16* Vh = Vt + (size_t)bh * DH_ * T_;

        // Q A-frags: lane holds Q[q0+lo][half*32 + qd*8 + j]
        bf16x8 qa0 = *(const bf16x8*)(Qh + (size_t)(q0 + lo) * DH_ + qd * 8);
        bf16x8 qa1 = *(const bf16x8*)(Qh + (size_t)(q0 + lo) * DH_ + 32 + qd * 8);

        f32x4 oacc[4] = {};
        float m = -1e30f;
        float lrow[4] = {0.0f, 0.0f, 0.0f, 0.0f};
        const int qrow  = q0 + qd * 4;
        const int ntile = x + 1;

        // prologue: stage tile 0 into buffer 0 (prev item fully synced)
        GLOAD16(Kh + (size_t)r0s * DH_ + c0s * 8, Ks[0] + so0);
        GLOAD16(Kh + (size_t)r1s * DH_ + c1s * 8, Ks[0] + so1);
        GLOAD16(Vh + (size_t)r0s * T_ + c0s * 8, Vs[0] + so0);
        GLOAD16(Vh + (size_t)r1s * T_ + c1s * 8, Vs[0] + so1);
        DRAIN_ALL();
        __syncthreads();

        for (int t = 0; t < ntile; t++) {
            const int j0  = t << 6;
            const int cur = t & 1;
            if (t + 1 < ntile) {         // prefetch next K/V tile
                const int j0n = j0 + 64;
                GLOAD16(Kh + (size_t)(j0n + r0s) * DH_ + c0s * 8, Ks[1 - cur] + so0);
                GLOAD16(Kh + (size_t)(j0n + r1s) * DH_ + c1s * 8, Ks[1 - cur] + so1);
                GLOAD16(Vh + (size_t)r0s * T_ + j0n + c0s * 8, Vs[1 - cur] + so0);
                GLOAD16(Vh + (size_t)r1s * T_ + j0n + c1s * 8, Vs[1 - cur] + so1);
            }

            // ---- S = Q @ K^T, 64 keys as 4 col-groups of 16 ----
            f32x4 s[4] = {};
#pragma unroll
            for (int g = 0; g < 4; g++) {
                const int row = g * 16 + lo;
                const __bf16* kr = Ks[cur] + row * 64;
                bf16x8 kb0 = *(const bf16x8*)(kr + ((qd ^ (row & 7)) << 3));
                bf16x8 kb1 = *(const bf16x8*)(kr + (((4 + qd) ^ (row & 7)) << 3));
                s[g] = MFMA16(qa0, kb0, s[g]);
                s[g] = MFMA16(qa1, kb1, s[g]);
            }

            // ---- causal mask (diagonal tile only; wave-uniform gate) ----
            if (j0 + 63 > q0) {
#pragma unroll
                for (int g = 0; g < 4; g++) {
                    const int col = j0 + g * 16 + lo;
#pragma unroll
                    for (int r = 0; r < 4; r++)
                        s[g][r] = (col <= qrow + r) ? s[g][r] : -1e30f;
                }
            }

            // ---- shared per-wave max (exact: m arbitrary if consistent) ----
            float lm = s[0][0];
#pragma unroll
            for (int g = 0; g < 4; g++)
#pragma unroll
                for (int r = 0; r < 4; r++) lm = fmaxf(lm, s[g][r]);
#pragma unroll
            for (int off = 1; off < 64; off <<= 1)
                lm = fmaxf(lm, __shfl_xor(lm, off));
            const float mnew = fmaxf(m, lm);
            if (mnew > m) {              // wave-uniform; skipped once m settles
                const float alpha = __builtin_amdgcn_exp2f(m - mnew);
#pragma unroll
                for (int r = 0; r < 4; r++) lrow[r] *= alpha;
#pragma unroll
                for (int c = 0; c < 4; c++)
#pragma unroll
                    for (int r = 0; r < 4; r++) oacc[c][r] *= alpha;
                m = mnew;
            }

            // ---- P = exp2(S - m): C-layout -> per-wave LDS -> A-layout ----
#pragma unroll
            for (int g = 0; g < 4; g++)
#pragma unroll
                for (int r = 0; r < 4; r++)
                    Ps[wave][qd * 4 + r][g * 16 + lo] =
                        (__bf16)__builtin_amdgcn_exp2f(s[g][r] - m);
            __asm__ volatile("s_waitcnt lgkmcnt(0)" ::: "memory");
            bf16x8 pa0 = *(const bf16x8*)(&Ps[wave][lo][qd * 8]);
            bf16x8 pa1 = *(const bf16x8*)(&Ps[wave][lo][32 + qd * 8]);

            // ---- row sums via MFMA ones-trick + O += P @ V ----
            f32x4 ps = {};
            ps = MFMA16(pa0, ones, ps);
            ps = MFMA16(pa1, ones, ps);
#pragma unroll
            for (int c = 0; c < 4; c++) {
                const int row = c * 16 + lo;
                const __bf16* vr = Vs[cur] + row * 64;
                bf16x8 vb0 = *(const bf16x8*)(vr + ((qd ^ (row & 7)) << 3));
                bf16x8 vb1 = *(const bf16x8*)(vr + (((4 + qd) ^ (row & 7)) << 3));
                oacc[c] = MFMA16(pa0, vb0, oacc[c]);
                oacc[c] = MFMA16(pa1, vb1, oacc[c]);
            }
#pragma unroll
            for (int r = 0; r < 4; r++) lrow[r] += ps[r];

            DRAIN_ALL();                 // prefetch landed + all LDS ops done
            __syncthreads();
        }

        // ---- normalize + store O as [B][T][H*64] bf16 ----
        float inv[4];
#pragma unroll
        for (int r = 0; r < 4; r++) inv[r] = 1.0f / lrow[r];
#pragma unroll
        for (int c = 0; c < 4; c++) {
#pragma unroll
            for (int r = 0; r < 4; r++) {
                float val = oacc[c][r] * inv[r];
                size_t idx = ((size_t)b * T_ + (qrow + r)) * D_ + h * DH_ + c * 16 + lo;
                O[idx] = (__bf16)val;
            }
        }
    }
}

// -------------------------------- launcher ---------------------------------

extern "C" void kernel_launch(void* const* d_in, const int* in_sizes, int n_in,
                              void* d_out, int out_size, void* d_ws, size_t ws_size,
                              hipStream_t stream) {
    const float* x      = (const float*)d_in[0];
    const float* w_attn = (const float*)d_in[1];
    const float* b_attn = (const float*)d_in[2];
    const float* w_proj = (const float*)d_in[3];
    const float* b_proj = (const float*)d_in[4];
    float* out = (float*)d_out;

    const size_t MB = (size_t)1 << 20;
    if (ws_size < 48 * MB) return;   // need 48 MB scratch

    char* ws = (char*)d_ws;
    __bf16* xb     = (__bf16*)(ws);              //  8 MB  [M][D]
    __bf16* wattnT = (__bf16*)(ws + 8 * MB);     //  6 MB  [3D][D]
    __bf16* wprojT = (__bf16*)(ws + 14 * MB);    //  2 MB  [D][D]
    __bf16* Qb     = (__bf16*)(ws + 16 * MB);    //  8 MB  [BH][T][64]
    __bf16* Kb     = (__bf16*)(ws + 24 * MB);    //  8 MB  [BH][T][64]
    __bf16* Vt     = (__bf16*)(ws + 32 * MB);    //  8 MB  [BH][64][T]
    __bf16* Ob     = (__bf16*)(ws + 40 * MB);    //  8 MB  [M][D]

    // 1. converts (x -> bf16; both weight transposes in one launch)
    f32_to_bf16_kernel<<<(M_ * D_) / 1024, 256, 0, stream>>>(x, xb, M_ * D_);
    transpose2_bf16_kernel<<<dim3((N1_ + D_) / 32, D_ / 32), dim3(32, 8), 0, stream>>>(
        w_attn, wattnT, w_proj, wprojT);
    // 2. QKV GEMM -> Q(scaled)/K/Vt
    gemm_bt_kernel<0, 128><<<dim3(N1_ / 128, M_ / 128), 256, 0, stream>>>(
        xb, wattnT, b_attn, nullptr, Qb, Kb, Vt, M_, N1_, D_);
    // 3. causal flash attention (persistent snake schedule, 3 blocks/CU)
    attn_kernel<<<dim3(768), 256, 0, stream>>>(Qb, Kb, Vt, Ob);
    // 4. output projection (fp32 + bias), 64-row tiles for 2 blocks/CU
    gemm_bt_kernel<1, 64><<<dim3(D_ / 128, M_ / 64), 256, 0, stream>>>(
        Ob, wprojT, b_proj, out, nullptr, nullptr, nullptr, M_, D_, D_);
}